// Round 3
// baseline (43.172 us; speedup 1.0000x reference)
//
#include <hip/hip_runtime.h>
#include <hip/hip_bf16.h>
#include <stdint.h>

#define TSTEPS   4096
#define C_CHUNKS 128
#define L_STEPS  32          // TSTEPS / C_CHUNKS
#define JROW     104         // padded LDS row (101 used)

__device__ __forceinline__ float fast_exp2(float x){ return __builtin_amdgcn_exp2f(x); }
__device__ __forceinline__ float fast_rcp (float x){ return __builtin_amdgcn_rcpf(x); }
__device__ __forceinline__ float sigmoid_f(float x){
  return fast_rcp(1.0f + fast_exp2(-1.4426950408889634f * x));
}

// Build this chunk's fused g-table in LDS and return the wave-uniform up-mask.
//   tabs[tl][j] = up_t ?  sigmoid((h_t - j*0.01)/temp)   : -sigmoid((j*0.01 - h_t)/temp)
// A step is then s' = (1-|v|)*s + v with v = tabs[tl][ up ? ia : ib ].
__device__ __forceinline__ uint32_t build_table(
    const float* __restrict__ h, int t0, float (*tabs)[JROW], int tid)
{
  const float C = 144.26950408889634f;   // (1/temp) * log2(e)

  // wave-uniform up-mask via ballot (lanes 0..31 supply the bits)
  const int  lane = tid & 63;
  bool bit = false;
  if (lane < L_STEPS) {
    const int t = t0 + lane;
    const float ht = h[t];
    const float hp = (t > 0) ? h[t - 1] : 0.0f;
    bit = ht > hp;
  }
  const uint32_t um = (uint32_t)(__ballot(bit) & 0xffffffffull);

  // 32 rows x 128 slots = 4096 items, 16 per thread (j<=100 populated)
  #pragma unroll
  for (int pass = 0; pass < 16; ++pass) {
    const int item = pass * 256 + tid;
    const int trel = item >> 7;
    const int j    = item & 127;
    if (j <= 100) {
      const int   t  = t0 + trel;
      const float ht = h[t];
      const float hp = (t > 0) ? h[t - 1] : 0.0f;
      const bool  up = ht > hp;
      const float x  = (float)j * 0.01f;
      const float arg = up ? (x - ht) * C : (ht - x) * C;
      const float g   = fast_rcp(1.0f + fast_exp2(arg));
      tabs[trel][j] = up ? g : -g;
    }
  }
  __syncthreads();
  return um;
}

// KA: per (point-block, chunk): build LDS table, compose the 32 affine steps
// into (A,B). Block (0,0) also computes D = sum(sigmoid(density)) and the
// affine output base h*slope + offset.
__global__ __launch_bounds__(256) void kA_affine(
    const float* __restrict__ h, const float* __restrict__ mesh,
    const float* __restrict__ raw_density, const float* __restrict__ raw_offset,
    const float* __restrict__ raw_slope,
    int N, int Np, float* __restrict__ Aw, float* __restrict__ Bw,
    float* __restrict__ Dws, float* __restrict__ out)
{
  __shared__ float tabs[L_STEPS][JROW];
  const int tid = threadIdx.x;
  const int i   = blockIdx.x * 256 + tid;
  const int c   = blockIdx.y;
  const uint32_t um = build_table(h, c * L_STEPS, tabs, tid);

  float beta = 0.f, alpha = 0.f;
  if (i < N) { beta = mesh[2*i]; alpha = mesh[2*i+1]; }
  const int ia = (int)(alpha * 100.0f + 0.5f);
  const int ib = (int)(beta  * 100.0f + 0.5f);

  float A = 1.0f, B = 0.0f;
  #pragma unroll
  for (int tl = 0; tl < L_STEPS; ++tl) {
    const float v = tabs[tl][((um >> tl) & 1u) ? ia : ib];
    const float a = 1.0f - fabsf(v);
    A = A * a;
    B = fmaf(a, B, v);
  }
  Aw[(size_t)c * Np + i] = A;
  Bw[(size_t)c * Np + i] = B;

  if (blockIdx.x == 0 && c == 0) {
    __shared__ float red[256];
    float loc = 0.f;
    for (int j = tid; j < N; j += 256) loc += sigmoid_f(raw_density[j]);
    red[tid] = loc;
    __syncthreads();
    for (int st = 128; st > 0; st >>= 1) {
      if (tid < st) red[tid] += red[tid + st];
      __syncthreads();
    }
    if (tid == 0) Dws[0] = red[0];
    const float offset = -10.0f + 20.0f * sigmoid_f(raw_offset[0]);
    const float slope  = -20.0f + 40.0f * sigmoid_f(raw_slope[0]);
    for (int t = tid; t < TSTEPS; t += 256) out[t] = fmaf(h[t], slope, offset);
  }
}

// K2: sequential scan over chunks per point; writes chunk-start states.
__global__ __launch_bounds__(256) void k2_scan(
    const float* __restrict__ Aw, const float* __restrict__ Bw,
    float* __restrict__ Sw, int Np)
{
  const int i = blockIdx.x * 256 + threadIdx.x;
  float s = -1.0f;
  #pragma unroll 8
  for (int c = 0; c < C_CHUNKS; ++c) {
    const size_t off = (size_t)c * Np + i;
    Sw[off] = s;
    s = fmaf(Aw[off], s, Bw[off]);
  }
}

// KB: per (point-block, chunk): rebuild LDS table, recompute the 32 states
// from the chunk-start state, weight by d_i, butterfly transpose-reduce over
// the wave's 64 points, atomicAdd (scale/D)*partial into out.
__global__ __launch_bounds__(256) void kB_states(
    const float* __restrict__ h, const float* __restrict__ mesh,
    const float* __restrict__ raw_density, const float* __restrict__ Sw,
    const float* __restrict__ Dws, const float* __restrict__ raw_scale,
    int N, int Np, float* __restrict__ out)
{
  __shared__ float tabs[L_STEPS][JROW];
  const int tid  = threadIdx.x;
  const int i    = blockIdx.x * 256 + tid;
  const int c    = blockIdx.y;
  const int lane = tid & 63;
  const int t0   = c * L_STEPS;
  const uint32_t um = build_table(h, t0, tabs, tid);

  float beta = 0.f, alpha = 0.f, d = 0.f;
  if (i < N) { beta = mesh[2*i]; alpha = mesh[2*i+1]; d = sigmoid_f(raw_density[i]); }
  const int ia = (int)(alpha * 100.0f + 0.5f);
  const int ib = (int)(beta  * 100.0f + 0.5f);

  float s = Sw[(size_t)c * Np + i];
  float cur[L_STEPS];
  #pragma unroll
  for (int tl = 0; tl < L_STEPS; ++tl) {
    const float v = tabs[tl][((um >> tl) & 1u) ? ia : ib];
    const float a = 1.0f - fabsf(v);
    s = fmaf(a, s, v);
    cur[tl] = d * s;
  }

  // transpose-reduce: 5 butterfly stages over cur[32], then fold half-waves.
  // Lane l (l<32) ends holding the wave's 64-point sum of cur[l].
  #pragma unroll
  for (int k = 0; k < 5; ++k) {
    const bool bb = (lane >> k) & 1;
    #pragma unroll
    for (int j = 0; j < (L_STEPS >> (k + 1)); ++j) {
      const float x = bb ? cur[2*j + 1] : cur[2*j];
      const float y = bb ? cur[2*j]     : cur[2*j + 1];
      cur[j] = x + __shfl_xor(y, 1 << k, 64);
    }
  }
  const float val = cur[0] + __shfl_xor(cur[0], 32, 64);

  const float coef = 20.0f * sigmoid_f(raw_scale[0]) / Dws[0];
  if (lane < L_STEPS) atomicAdd(&out[t0 + lane], coef * val);
}

extern "C" void kernel_launch(void* const* d_in, const int* in_sizes, int n_in,
                              void* d_out, int out_size, void* d_ws, size_t ws_size,
                              hipStream_t stream)
{
  const float* h           = (const float*)d_in[0];
  const float* mesh        = (const float*)d_in[1];
  const float* raw_density = (const float*)d_in[2];
  const float* raw_offset  = (const float*)d_in[3];
  const float* raw_scale   = (const float*)d_in[4];
  const float* raw_slope   = (const float*)d_in[5];
  float* out = (float*)d_out;

  const int N  = in_sizes[2];          // 5151 mesh points
  const int P  = (N + 255) / 256;      // 21 point-blocks
  const int Np = P * 256;              // 5376 padded points

  float* ws  = (float*)d_ws;
  float* Aw  = ws;                                   // C*Np
  float* Bw  = Aw + (size_t)C_CHUNKS * Np;           // C*Np
  float* Sw  = Bw + (size_t)C_CHUNKS * Np;           // C*Np
  float* Dws = Sw + (size_t)C_CHUNKS * Np;           // 1

  dim3 gridPC(P, C_CHUNKS);
  kA_affine<<<gridPC, 256, 0, stream>>>(h, mesh, raw_density, raw_offset,
                                        raw_slope, N, Np, Aw, Bw, Dws, out);
  k2_scan  <<<P,      256, 0, stream>>>(Aw, Bw, Sw, Np);
  kB_states<<<gridPC, 256, 0, stream>>>(h, mesh, raw_density, Sw, Dws,
                                        raw_scale, N, Np, out);
}

// Round 4
// 42.361 us; speedup vs baseline: 1.0191x; 1.0191x over previous
//
#include <hip/hip_runtime.h>
#include <hip/hip_bf16.h>
#include <stdint.h>

#define TSTEPS   4096
#define C_CHUNKS 128
#define L_STEPS  32          // TSTEPS / C_CHUNKS
#define JPAD     128         // padded row width of the g-table (101 used)

__device__ __forceinline__ float fast_exp2(float x){ return __builtin_amdgcn_exp2f(x); }
__device__ __forceinline__ float fast_rcp (float x){ return __builtin_amdgcn_rcpf(x); }
__device__ __forceinline__ float sigmoid_f(float x){
  return fast_rcp(1.0f + fast_exp2(-1.4426950408889634f * x));
}

// K0: build the fused g-table (global, built ONCE — round-3 post-mortem:
// per-block LDS rebuild costs 40x the transcendental work to save one
// launch; keep the global table), the up-mask, D = sum(sigmoid(density)),
// and the affine base of the output.
//   tab[t][j] = up_t ?  sigmoid((h_t - j*0.01)/temp)     (alpha table, +g)
//            : -sigmoid((j*0.01 - h_t)/temp)             (beta  table, -g)
// Then a step is s' = (1-|v|)*s + v for v = tab[t][idx], idx = up? ia : ib.
__global__ __launch_bounds__(256) void k0_prep(
    const float* __restrict__ h, const float* __restrict__ raw_density,
    const float* __restrict__ raw_offset, const float* __restrict__ raw_scale,
    const float* __restrict__ raw_slope,
    int N, float* __restrict__ tab, uint32_t* __restrict__ umask,
    float* __restrict__ Dws, float* __restrict__ out)
{
  const int tid = threadIdx.x;
  const int c   = blockIdx.x;           // one block per chunk of 32 t
  const int t0  = c * L_STEPS;
  const float C = 144.26950408889634f;  // (1/temp) * log2(e)

  // up-mask for this chunk (wave 0, lanes 0..31)
  if (tid < 64) {
    const int  l    = tid;
    const int  t    = t0 + l;
    bool bit = false;
    if (l < L_STEPS) {
      const float ht = h[t];
      const float hp = (t > 0) ? h[t - 1] : 0.0f;
      bit = ht > hp;
    }
    const uint64_t m = __ballot(bit);
    if (l == 0) umask[c] = (uint32_t)(m & 0xffffffffull);
  }

  // table rows t0..t0+31 (32 t x 128 j = 4096 items, 16 per thread)
  #pragma unroll
  for (int pass = 0; pass < 16; ++pass) {
    const int item = pass * 256 + tid;
    const int trel = item >> 7;        // /128
    const int j    = item & 127;
    if (j <= 100) {
      const int   t  = t0 + trel;
      const float ht = h[t];
      const float hp = (t > 0) ? h[t - 1] : 0.0f;
      const bool  up = ht > hp;
      const float x  = (float)j * 0.01f;
      const float arg = up ? (x - ht) * C : (ht - x) * C;
      const float g   = fast_rcp(1.0f + fast_exp2(arg));
      tab[(size_t)t * JPAD + j] = up ? g : -g;
    }
  }

  // block 0: density normalizer + output affine base
  if (c == 0) {
    __shared__ float red[256];
    float loc = 0.f;
    for (int j = tid; j < N; j += 256) loc += sigmoid_f(raw_density[j]);
    red[tid] = loc;
    __syncthreads();
    for (int st = 128; st > 0; st >>= 1) {
      if (tid < st) red[tid] += red[tid + st];
      __syncthreads();
    }
    if (tid == 0) Dws[0] = red[0];
    const float offset = -10.0f + 20.0f * sigmoid_f(raw_offset[0]);
    const float slope  = -20.0f + 40.0f * sigmoid_f(raw_slope[0]);
    for (int t = tid; t < TSTEPS; t += 256) out[t] = fmaf(h[t], slope, offset);
  }
}

// K1: per (point, chunk) affine composition over L_STEPS steps via table.
__global__ __launch_bounds__(256) void k1_affine(
    const float* __restrict__ tab, const uint32_t* __restrict__ umask,
    const float* __restrict__ mesh,
    int N, int Np, float* __restrict__ Aw, float* __restrict__ Bw)
{
  const int tid = threadIdx.x;
  const int i   = blockIdx.x * 256 + tid;
  const int c   = blockIdx.y;

  float beta = 0.f, alpha = 0.f;
  if (i < N) { beta = mesh[2*i]; alpha = mesh[2*i+1]; }
  const int ia = (int)(alpha * 100.0f + 0.5f);
  const int ib = (int)(beta  * 100.0f + 0.5f);

  const uint32_t um   = umask[c];
  const float*   tabc = tab + (size_t)c * L_STEPS * JPAD;

  float A = 1.0f, B = 0.0f;
  #pragma unroll
  for (int tl = 0; tl < L_STEPS; ++tl) {
    const int   idx = ((um >> tl) & 1u) ? ia : ib;
    const float v   = tabc[tl * JPAD + idx];
    const float a   = 1.0f - fabsf(v);
    A = A * a;
    B = fmaf(a, B, v);
  }
  Aw[(size_t)c * Np + i] = A;
  Bw[(size_t)c * Np + i] = B;
}

// K2: sequential scan over chunks per point (writes chunk-start states).
__global__ __launch_bounds__(256) void k2_scan(
    const float* __restrict__ Aw, const float* __restrict__ Bw,
    float* __restrict__ Sw, int Np)
{
  const int i = blockIdx.x * 256 + threadIdx.x;
  float s = -1.0f;
  #pragma unroll 8
  for (int c = 0; c < C_CHUNKS; ++c) {
    const size_t off = (size_t)c * Np + i;
    Sw[off] = s;
    s = fmaf(Aw[off], s, Bw[off]);
  }
}

// K3: recompute states per chunk from the chunk-start state, weight by d_i,
// butterfly transpose-reduce over the wave's 64 points, atomicAdd into out.
__global__ __launch_bounds__(256) void k3_states(
    const float* __restrict__ tab, const uint32_t* __restrict__ umask,
    const float* __restrict__ mesh, const float* __restrict__ raw_density,
    const float* __restrict__ Sw, const float* __restrict__ Dws,
    const float* __restrict__ raw_scale,
    int N, int Np, float* __restrict__ out)
{
  const int tid  = threadIdx.x;
  const int i    = blockIdx.x * 256 + tid;
  const int c    = blockIdx.y;
  const int lane = tid & 63;
  const int t0   = c * L_STEPS;

  float beta = 0.f, alpha = 0.f, d = 0.f;
  if (i < N) { beta = mesh[2*i]; alpha = mesh[2*i+1]; d = sigmoid_f(raw_density[i]); }
  const int ia = (int)(alpha * 100.0f + 0.5f);
  const int ib = (int)(beta  * 100.0f + 0.5f);

  const uint32_t um   = umask[c];
  const float*   tabc = tab + (size_t)c * L_STEPS * JPAD;

  float s = Sw[(size_t)c * Np + i];
  float cur[L_STEPS];
  #pragma unroll
  for (int tl = 0; tl < L_STEPS; ++tl) {
    const int   idx = ((um >> tl) & 1u) ? ia : ib;
    const float v   = tabc[tl * JPAD + idx];
    const float a   = 1.0f - fabsf(v);
    s = fmaf(a, s, v);
    cur[tl] = d * s;
  }

  // transpose-reduce: 5 stages over cur[32], then fold the two half-waves.
  // Lane l (l<32) ends holding sum over the wave's 64 points of cur[l].
  #pragma unroll
  for (int k = 0; k < 5; ++k) {
    const bool bb = (lane >> k) & 1;
    #pragma unroll
    for (int j = 0; j < (L_STEPS >> (k + 1)); ++j) {
      const float x = bb ? cur[2*j + 1] : cur[2*j];
      const float y = bb ? cur[2*j]     : cur[2*j + 1];
      cur[j] = x + __shfl_xor(y, 1 << k, 64);
    }
  }
  const float val = cur[0] + __shfl_xor(cur[0], 32, 64);

  const float scale = 20.0f * sigmoid_f(raw_scale[0]);
  const float coef  = scale / Dws[0];
  if (lane < L_STEPS) atomicAdd(&out[t0 + lane], coef * val);
}

extern "C" void kernel_launch(void* const* d_in, const int* in_sizes, int n_in,
                              void* d_out, int out_size, void* d_ws, size_t ws_size,
                              hipStream_t stream)
{
  const float* h           = (const float*)d_in[0];
  const float* mesh        = (const float*)d_in[1];
  const float* raw_density = (const float*)d_in[2];
  const float* raw_offset  = (const float*)d_in[3];
  const float* raw_scale   = (const float*)d_in[4];
  const float* raw_slope   = (const float*)d_in[5];
  float* out = (float*)d_out;

  const int N  = in_sizes[2];          // 5151 mesh points
  const int P  = (N + 255) / 256;      // 21 point-blocks
  const int Np = P * 256;              // 5376 padded points

  float* ws   = (float*)d_ws;
  float* tab  = ws;                                    // TSTEPS*JPAD
  float* Aw   = tab + (size_t)TSTEPS * JPAD;           // C*Np
  float* Bw   = Aw  + (size_t)C_CHUNKS * Np;           // C*Np
  float* Sw   = Bw  + (size_t)C_CHUNKS * Np;           // C*Np
  float* Dws  = Sw  + (size_t)C_CHUNKS * Np;           // 1
  uint32_t* umask = (uint32_t*)(Dws + 1);              // C_CHUNKS

  dim3 gridPC(P, C_CHUNKS);
  k0_prep  <<<C_CHUNKS, 256, 0, stream>>>(h, raw_density, raw_offset, raw_scale,
                                          raw_slope, N, tab, umask, Dws, out);
  k1_affine<<<gridPC,  256, 0, stream>>>(tab, umask, mesh, N, Np, Aw, Bw);
  k2_scan  <<<P,       256, 0, stream>>>(Aw, Bw, Sw, Np);
  k3_states<<<gridPC,  256, 0, stream>>>(tab, umask, mesh, raw_density, Sw, Dws,
                                         raw_scale, N, Np, out);
}